// Round 6
// baseline (1389.158 us; speedup 1.0000x reference)
//
#include <hip/hip_runtime.h>

#define N_NODES 50000
#define N_EDGES 800000
#define N_GRAPHS 500
#define BN_EPS 1e-5f
#define F 256
#define SCAN_BLOCKS ((N_NODES + 255) / 256)   // 196
#define NPART 64                              // stats atomic partitions

typedef short short8 __attribute__((ext_vector_type(8)));
typedef float f32x4 __attribute__((ext_vector_type(4)));
typedef _Float16 h16x8 __attribute__((ext_vector_type(8)));

// ---------------- degree histogram (int) ----------------
__global__ void k_hist(const int* __restrict__ dst, int* __restrict__ cnt) {
    int e = blockIdx.x * blockDim.x + threadIdx.x;
    if (e < N_EDGES) atomicAdd(&cnt[dst[e]], 1);
}

__global__ void k_dinv(const int* __restrict__ cnt, float* __restrict__ dinv) {
    int n = blockIdx.x * blockDim.x + threadIdx.x;
    if (n < N_NODES) dinv[n] = rsqrtf((float)cnt[n] + 1.0f);
}

// ---------------- prefix scan ----------------
__global__ void k_scan1(const int* __restrict__ cnt, int* __restrict__ rowptr,
                        int* __restrict__ bsum) {
    __shared__ int s[256];
    int tid = threadIdx.x;
    int i = blockIdx.x * 256 + tid;
    int v = (i < N_NODES) ? cnt[i] : 0;
    s[tid] = v;
    __syncthreads();
    for (int off = 1; off < 256; off <<= 1) {
        int add = (tid >= off) ? s[tid - off] : 0;
        __syncthreads();
        s[tid] += add;
        __syncthreads();
    }
    if (i < N_NODES) rowptr[i] = s[tid] - v;
    if (tid == 255) bsum[blockIdx.x] = s[255];
}

__global__ void k_scan2(int* __restrict__ bsum) {
    __shared__ int s[256];
    int tid = threadIdx.x;
    int v = (tid < SCAN_BLOCKS) ? bsum[tid] : 0;
    s[tid] = v;
    __syncthreads();
    for (int off = 1; off < 256; off <<= 1) {
        int add = (tid >= off) ? s[tid - off] : 0;
        __syncthreads();
        s[tid] += add;
        __syncthreads();
    }
    if (tid < SCAN_BLOCKS) bsum[tid] = s[tid] - v;
}

__global__ void k_scan3(int* __restrict__ rowptr, const int* __restrict__ bsum) {
    int i = blockIdx.x * 256 + threadIdx.x;
    if (i < N_NODES) rowptr[i] += bsum[blockIdx.x];
    if (i == 0) rowptr[N_NODES] = N_EDGES;
}

// ---------------- scatter edges into CSR: pack (src, norm) into int2 ---------
__global__ void k_scatter(const int* __restrict__ src, const int* __restrict__ dst,
                          const float* __restrict__ dinv, const int* __restrict__ rowptr,
                          int* __restrict__ fill, int2* __restrict__ epair) {
    int e = blockIdx.x * 256 + threadIdx.x;
    if (e >= N_EDGES) return;
    int s = src[e], d = dst[e];
    int slot = rowptr[d] + atomicAdd(&fill[d], 1);
    epair[slot] = make_int2(s, __float_as_int(dinv[s] * dinv[d]));
}

// ---------------- weight prepack: W[K][256] f32 -> Wt_hi/Wt_lo [256][K] bf16 --
__global__ void k_pack(const float* __restrict__ W, short* __restrict__ hi,
                       short* __restrict__ lo, int K) {
    int idx = blockIdx.x * 256 + threadIdx.x;
    if (idx >= 256 * K) return;
    int n = idx / K, k = idx - n * K;
    float f = W[(size_t)k * 256 + n];
    unsigned u = __builtin_bit_cast(unsigned, f);
    hi[idx] = (short)(u >> 16);
    float hf = __builtin_bit_cast(float, u & 0xFFFF0000u);
    lo[idx] = (short)(__builtin_bit_cast(unsigned, f - hf) >> 16);
}

// ---------------- split-bf16 MFMA GEMM, fused BN-apply on A, fp16 C ----------
// grid: 784 blocks; bid remapped so the 2 col-blocks of the same rows land on
// the same XCD (ids differ by 8 under round-robin dispatch) for A L2 reuse.
#define BK 32
__global__ __launch_bounds__(256)
void k_gemm_mfma(const float* __restrict__ A, const short* __restrict__ Bhi,
                 const short* __restrict__ Blo, _Float16* __restrict__ C,
                 int M, int K,
                 const float* __restrict__ mulk, const float* __restrict__ addk) {
    __shared__ unsigned As[2][128 * 16];
    const int tid  = threadIdx.x;
    const int lane = tid & 63;
    const int w    = tid >> 6;
    const int wr   = (w >> 1) * 64;
    const int wc   = (w & 1) * 64;
    const int bid  = blockIdx.x;
    const int bx   = (bid >> 4) * 8 + (bid & 7);   // 0..391
    const int by   = (bid >> 3) & 1;
    const int brow = bx * 128;
    const int bcol = by * 128;

    f32x4 acc[4][4];
    #pragma unroll
    for (int m = 0; m < 4; ++m)
        #pragma unroll
        for (int n = 0; n < 4; ++n) acc[m][n] = (f32x4){0.f, 0.f, 0.f, 0.f};

    const int lr = tid >> 1;
    const int lk = (tid & 1) * 16;
    const int grow = brow + lr;
    const bool rowok = grow < M;
    const float* Aptr = A + (size_t)grow * K + lk;
    const int NS = K / BK;

    float4 pf0, pf1, pf2, pf3;
    auto load_pf = [&](int s) {
        if (rowok) {
            const float* p = Aptr + s * BK;
            pf0 = *reinterpret_cast<const float4*>(p);
            pf1 = *reinterpret_cast<const float4*>(p + 4);
            pf2 = *reinterpret_cast<const float4*>(p + 8);
            pf3 = *reinterpret_cast<const float4*>(p + 12);
        } else {
            pf0 = pf1 = pf2 = pf3 = make_float4(0.f, 0.f, 0.f, 0.f);
        }
    };

    load_pf(0);

    for (int s = 0; s < NS; ++s) {
        __syncthreads();
        {
            float vals[16];
            vals[0]=pf0.x; vals[1]=pf0.y; vals[2]=pf0.z; vals[3]=pf0.w;
            vals[4]=pf1.x; vals[5]=pf1.y; vals[6]=pf1.z; vals[7]=pf1.w;
            vals[8]=pf2.x; vals[9]=pf2.y; vals[10]=pf2.z; vals[11]=pf2.w;
            vals[12]=pf3.x; vals[13]=pf3.y; vals[14]=pf3.z; vals[15]=pf3.w;
            if (mulk) {
                int kabs = s * BK + lk;
                #pragma unroll
                for (int q = 0; q < 4; ++q) {
                    float4 mk = *reinterpret_cast<const float4*>(&mulk[kabs + 4 * q]);
                    float4 ak = *reinterpret_cast<const float4*>(&addk[kabs + 4 * q]);
                    vals[4*q+0] = fmaf(vals[4*q+0], mk.x, ak.x);
                    vals[4*q+1] = fmaf(vals[4*q+1], mk.y, ak.y);
                    vals[4*q+2] = fmaf(vals[4*q+2], mk.z, ak.z);
                    vals[4*q+3] = fmaf(vals[4*q+3], mk.w, ak.w);
                }
            }
            unsigned hiw[8], low[8];
            #pragma unroll
            for (int p = 0; p < 8; ++p) {
                float f0 = vals[2*p], f1 = vals[2*p+1];
                unsigned u0 = __builtin_bit_cast(unsigned, f0);
                unsigned u1 = __builtin_bit_cast(unsigned, f1);
                hiw[p] = (u1 & 0xFFFF0000u) | (u0 >> 16);
                float h0 = __builtin_bit_cast(float, u0 & 0xFFFF0000u);
                float h1 = __builtin_bit_cast(float, u1 & 0xFFFF0000u);
                unsigned l0 = __builtin_bit_cast(unsigned, f0 - h0);
                unsigned l1 = __builtin_bit_cast(unsigned, f1 - h1);
                low[p] = (l1 & 0xFFFF0000u) | (l0 >> 16);
            }
            const int sw = (lr >> 1) & 3;
            const int c0 = (tid & 1) * 2;
            unsigned* dh0 = &As[0][lr * 16 + ((c0 ^ sw) << 2)];
            unsigned* dh1 = &As[0][lr * 16 + (((c0 + 1) ^ sw) << 2)];
            unsigned* dl0 = &As[1][lr * 16 + ((c0 ^ sw) << 2)];
            unsigned* dl1 = &As[1][lr * 16 + (((c0 + 1) ^ sw) << 2)];
            *reinterpret_cast<uint4*>(dh0) = make_uint4(hiw[0], hiw[1], hiw[2], hiw[3]);
            *reinterpret_cast<uint4*>(dh1) = make_uint4(hiw[4], hiw[5], hiw[6], hiw[7]);
            *reinterpret_cast<uint4*>(dl0) = make_uint4(low[0], low[1], low[2], low[3]);
            *reinterpret_cast<uint4*>(dl1) = make_uint4(low[4], low[5], low[6], low[7]);
        }
        if (s + 1 < NS) load_pf(s + 1);
        __syncthreads();

        short8 bh[4], bl[4];
        const int kb = s * BK + (lane >> 4) * 8;
        #pragma unroll
        for (int n = 0; n < 4; ++n) {
            int col = bcol + wc + n * 16 + (lane & 15);
            bh[n] = *reinterpret_cast<const short8*>(Bhi + (size_t)col * K + kb);
            bl[n] = *reinterpret_cast<const short8*>(Blo + (size_t)col * K + kb);
        }
        #pragma unroll
        for (int m = 0; m < 4; ++m) {
            int row = wr + m * 16 + (lane & 15);
            int c = lane >> 4;
            int sw = (row >> 1) & 3;
            const unsigned* ph = &As[0][row * 16 + ((c ^ sw) << 2)];
            const unsigned* pl = &As[1][row * 16 + ((c ^ sw) << 2)];
            short8 ah = *reinterpret_cast<const short8*>(ph);
            short8 al = *reinterpret_cast<const short8*>(pl);
            #pragma unroll
            for (int n = 0; n < 4; ++n) {
                acc[m][n] = __builtin_amdgcn_mfma_f32_16x16x32_bf16(ah, bh[n], acc[m][n], 0, 0, 0);
                acc[m][n] = __builtin_amdgcn_mfma_f32_16x16x32_bf16(al, bh[n], acc[m][n], 0, 0, 0);
                acc[m][n] = __builtin_amdgcn_mfma_f32_16x16x32_bf16(ah, bl[n], acc[m][n], 0, 0, 0);
            }
        }
    }

    #pragma unroll
    for (int m = 0; m < 4; ++m) {
        #pragma unroll
        for (int n = 0; n < 4; ++n) {
            int col = bcol + wc + n * 16 + (lane & 15);
            #pragma unroll
            for (int j = 0; j < 4; ++j) {
                int row = brow + wr + m * 16 + (lane >> 4) * 4 + j;
                if (row < M) C[(size_t)row * 256 + col] = (_Float16)acc[m][n][j];
            }
        }
    }
}

// ---------------- fused aggregation v3: one node per wave, high MLP ----------
// Wave split in halves: half h processes edges beg+2k+h. Lane owns 8 fp16
// features (16B loads). BATCH=8 pairs -> 8x16B in flight per lane. (src,norm)
// packed in int2. Cross-half merge via shfl_xor(32).
// MODE 0: h=relu(agg+bias) fp32 + BN stats into 64-way partitioned buffers.
// MODE 1: pooled into out via atomics.
#define BATCH 8
template<int MODE>
__global__ __launch_bounds__(256)
void k_agg2(const _Float16* __restrict__ xw, const float* __restrict__ dinv,
            const int* __restrict__ rowptr, const int2* __restrict__ epair,
            const float* __restrict__ bias, float* __restrict__ h,
            float* __restrict__ stats, const int* __restrict__ batch,
            float* __restrict__ out) {
    __shared__ float red[2][4][256];
    const int lane = threadIdx.x & 63;
    const int wave = threadIdx.x >> 6;
    const int half = lane >> 5;
    const int fl   = lane & 31;          // feature block: [8*fl, 8*fl+8)
    const int n    = blockIdx.x * 4 + wave;   // grid = 12500 exact

    const h16x8* xw8 = reinterpret_cast<const h16x8*>(xw);

    float acc[8];
    if (half == 0) {
        float d = dinv[n];
        float sl = d * d;
        h16x8 sv = xw8[(size_t)n * 32 + fl];
        #pragma unroll
        for (int j = 0; j < 8; ++j) acc[j] = sl * (float)sv[j];
    } else {
        #pragma unroll
        for (int j = 0; j < 8; ++j) acc[j] = 0.f;
    }

    const int beg = rowptr[n], end = rowptr[n + 1];
    int i = beg + half;

    if (i < end) {
        int ecur[BATCH]; float wcur[BATCH];
        #pragma unroll
        for (int k = 0; k < BATCH; ++k) {
            int idx = i + 2 * k;
            bool ok = idx < end;
            int2 p = epair[ok ? idx : (end - 1)];
            ecur[k] = p.x;
            wcur[k] = ok ? __int_as_float(p.y) : 0.f;
        }
        while (true) {
            h16x8 r[BATCH];
            #pragma unroll
            for (int k = 0; k < BATCH; ++k)
                r[k] = xw8[(size_t)ecur[k] * 32 + fl];

            int inext = i + 2 * BATCH;
            bool more = inext < end;
            int enxt[BATCH]; float wnxt[BATCH];
            if (more) {
                #pragma unroll
                for (int k = 0; k < BATCH; ++k) {
                    int idx = inext + 2 * k;
                    bool ok = idx < end;
                    int2 p = epair[ok ? idx : (end - 1)];
                    enxt[k] = p.x;
                    wnxt[k] = ok ? __int_as_float(p.y) : 0.f;
                }
            }
            #pragma unroll
            for (int k = 0; k < BATCH; ++k)
                #pragma unroll
                for (int j = 0; j < 8; ++j)
                    acc[j] = fmaf(wcur[k], (float)r[k][j], acc[j]);
            if (!more) break;
            i = inext;
            #pragma unroll
            for (int k = 0; k < BATCH; ++k) { ecur[k] = enxt[k]; wcur[k] = wnxt[k]; }
        }
    }

    // merge halves: every lane ends with the full sum for its 8 features
    #pragma unroll
    for (int j = 0; j < 8; ++j) acc[j] += __shfl_xor(acc[j], 32, 64);

    if (MODE == 0) {
        if (half == 0) {
            float4 b0 = *reinterpret_cast<const float4*>(&bias[fl * 8]);
            float4 b1 = *reinterpret_cast<const float4*>(&bias[fl * 8 + 4]);
            float bv[8] = {b0.x, b0.y, b0.z, b0.w, b1.x, b1.y, b1.z, b1.w};
            float4 o0, o1;
            #pragma unroll
            for (int j = 0; j < 8; ++j) {
                float v = fmaxf(acc[j] + bv[j], 0.f);
                acc[j] = v;
            }
            o0 = make_float4(acc[0], acc[1], acc[2], acc[3]);
            o1 = make_float4(acc[4], acc[5], acc[6], acc[7]);
            *reinterpret_cast<float4*>(&h[(size_t)n * 256 + fl * 8])     = o0;
            *reinterpret_cast<float4*>(&h[(size_t)n * 256 + fl * 8 + 4]) = o1;
            float4 q0 = make_float4(acc[0]*acc[0], acc[1]*acc[1], acc[2]*acc[2], acc[3]*acc[3]);
            float4 q1 = make_float4(acc[4]*acc[4], acc[5]*acc[5], acc[6]*acc[6], acc[7]*acc[7]);
            *reinterpret_cast<float4*>(&red[0][wave][fl * 8])     = o0;
            *reinterpret_cast<float4*>(&red[0][wave][fl * 8 + 4]) = o1;
            *reinterpret_cast<float4*>(&red[1][wave][fl * 8])     = q0;
            *reinterpret_cast<float4*>(&red[1][wave][fl * 8 + 4]) = q1;
        }
        __syncthreads();
        int t = threadIdx.x;
        float s = red[0][0][t] + red[0][1][t] + red[0][2][t] + red[0][3][t];
        float q = red[1][0][t] + red[1][1][t] + red[1][2][t] + red[1][3][t];
        float* part = stats + (size_t)(blockIdx.x & (NPART - 1)) * 512;
        atomicAdd(&part[t], s);
        atomicAdd(&part[256 + t], q);
    } else {
        if (half == 0) {
            float4 b0 = *reinterpret_cast<const float4*>(&bias[fl * 8]);
            float4 b1 = *reinterpret_cast<const float4*>(&bias[fl * 8 + 4]);
            float bv[8] = {b0.x, b0.y, b0.z, b0.w, b1.x, b1.y, b1.z, b1.w};
            int g = batch[n];
            #pragma unroll
            for (int j = 0; j < 8; ++j) {
                float v = fmaxf(acc[j] + bv[j], 0.f);
                atomicAdd(&out[(size_t)g * 256 + fl * 8 + j], v);
            }
        }
    }
}

// finalize: sum 64 partitions, produce mulk/addk
__global__ void k_bnfinalize(const float* __restrict__ stats,
                             const float* __restrict__ gamma, const float* __restrict__ beta,
                             float* __restrict__ mulk, float* __restrict__ addk) {
    int f = threadIdx.x;
    float s = 0.f, q = 0.f;
    for (int p = 0; p < NPART; ++p) {
        s += stats[(size_t)p * 512 + f];
        q += stats[(size_t)p * 512 + 256 + f];
    }
    float m = s * (1.0f / N_NODES);
    float var = q * (1.0f / N_NODES) - m * m;
    float sc = gamma[f] * rsqrtf(var + BN_EPS);
    mulk[f] = sc;
    addk[f] = beta[f] - m * sc;
}

// ---------------- host ----------------
extern "C" void kernel_launch(void* const* d_in, const int* in_sizes, int n_in,
                              void* d_out, int out_size, void* d_ws, size_t ws_size,
                              hipStream_t stream) {
    const float* x     = (const float*)d_in[0];
    const int*   ei    = (const int*)d_in[1];
    const int*   batch = (const int*)d_in[2];
    const float* W[6], *bias[6], *gamma[5], *beta[5];
    for (int i = 0; i < 6; ++i) {
        W[i]    = (const float*)d_in[3 + 2 * i];
        bias[i] = (const float*)d_in[4 + 2 * i];
    }
    for (int i = 0; i < 5; ++i) {
        gamma[i] = (const float*)d_in[15 + 2 * i];
        beta[i]  = (const float*)d_in[16 + 2 * i];
    }
    float* out = (float*)d_out;

    char* ws = (char*)d_ws;
    size_t off = 0;
    auto alloc = [&](size_t bytes) {
        void* p = ws + off;
        off = (off + bytes + 255) & ~(size_t)255;
        return p;
    };
    int*   cnt      = (int*)  alloc(N_NODES * 4);
    int*   rowptr   = (int*)  alloc((N_NODES + 1) * 4);
    int*   bsum     = (int*)  alloc(256 * 4);
    float* dinv     = (float*)alloc(N_NODES * 4);
    int2*  epair    = (int2*) alloc((size_t)N_EDGES * 8);
    float* mulk     = (float*)alloc(F * 4);
    float* addk     = (float*)alloc(F * 4);
    float* statsAll = (float*)alloc((size_t)5 * NPART * 512 * 4);   // 640 KB
    short* Whi[6]; short* Wlo[6];
    for (int l = 0; l < 6; ++l) {
        int K = (l == 0) ? 128 : 256;
        Whi[l] = (short*)alloc((size_t)256 * K * 2);
        Wlo[l] = (short*)alloc((size_t)256 * K * 2);
    }
    _Float16* bufA = (_Float16*)alloc((size_t)N_NODES * F * 2);   // xw fp16
    float*    bufB = (float*)   alloc((size_t)N_NODES * F * 4);   // h fp32

    const int* src = ei;
    const int* dst = ei + N_EDGES;

    // ---- CSR build + dinv + weight prepack ----
    hipMemsetAsync(cnt, 0, N_NODES * 4, stream);
    hipMemsetAsync(out, 0, (size_t)N_GRAPHS * F * 4, stream);
    hipMemsetAsync(statsAll, 0, (size_t)5 * NPART * 512 * 4, stream);
    k_hist<<<(N_EDGES + 255) / 256, 256, 0, stream>>>(dst, cnt);
    k_dinv<<<(N_NODES + 255) / 256, 256, 0, stream>>>(cnt, dinv);
    k_scan1<<<SCAN_BLOCKS, 256, 0, stream>>>(cnt, rowptr, bsum);
    k_scan2<<<1, 256, 0, stream>>>(bsum);
    k_scan3<<<SCAN_BLOCKS, 256, 0, stream>>>(rowptr, bsum);
    hipMemsetAsync(cnt, 0, N_NODES * 4, stream);
    k_scatter<<<(N_EDGES + 255) / 256, 256, 0, stream>>>(src, dst, dinv, rowptr, cnt, epair);
    for (int l = 0; l < 6; ++l) {
        int K = (l == 0) ? 128 : 256;
        k_pack<<<(256 * K + 255) / 256, 256, 0, stream>>>(W[l], Whi[l], Wlo[l], K);
    }

    const int aggGrid2 = N_NODES / 4;     // 12500 blocks of 4 waves
    const float* hin = x;
    for (int l = 0; l < 6; ++l) {
        const int K = (l == 0) ? 128 : 256;
        const float* mk = (l == 0) ? nullptr : mulk;
        const float* ak = (l == 0) ? nullptr : addk;
        k_gemm_mfma<<<784, 256, 0, stream>>>(hin, Whi[l], Wlo[l], bufA, N_NODES, K, mk, ak);

        if (l < 5) {
            float* stats = statsAll + (size_t)l * NPART * 512;
            k_agg2<0><<<aggGrid2, 256, 0, stream>>>(bufA, dinv, rowptr, epair,
                                                    bias[l], bufB, stats, batch, out);
            k_bnfinalize<<<1, F, 0, stream>>>(stats, gamma[l], beta[l], mulk, addk);
            hin = bufB;
        } else {
            k_agg2<1><<<aggGrid2, 256, 0, stream>>>(bufA, dinv, rowptr, epair,
                                                    bias[l], nullptr, nullptr, batch, out);
        }
    }
}

// Round 7
// 1145.229 us; speedup vs baseline: 1.2130x; 1.2130x over previous
//
#include <hip/hip_runtime.h>

#define N_NODES 50000
#define N_EDGES 800000
#define N_GRAPHS 500
#define BN_EPS 1e-5f
#define F 256
#define SCAN_BLOCKS ((N_NODES + 255) / 256)   // 196
#define NPART 64                              // stats atomic partitions

typedef short short8 __attribute__((ext_vector_type(8)));
typedef short short4v __attribute__((ext_vector_type(4)));
typedef float f32x4 __attribute__((ext_vector_type(4)));
typedef _Float16 h16x8 __attribute__((ext_vector_type(8)));

// ---------------- degree histogram (int) ----------------
__global__ void k_hist(const int* __restrict__ dst, int* __restrict__ cnt) {
    int e = blockIdx.x * blockDim.x + threadIdx.x;
    if (e < N_EDGES) atomicAdd(&cnt[dst[e]], 1);
}

// dinv + normsum init (normsum = dinv^2, scatter adds edge norms)
__global__ void k_dinv(const int* __restrict__ cnt, float* __restrict__ dinv,
                       float* __restrict__ normsum) {
    int n = blockIdx.x * blockDim.x + threadIdx.x;
    if (n < N_NODES) {
        float d = rsqrtf((float)cnt[n] + 1.0f);
        dinv[n] = d;
        normsum[n] = d * d;
    }
}

// ---------------- prefix scan ----------------
__global__ void k_scan1(const int* __restrict__ cnt, int* __restrict__ rowptr,
                        int* __restrict__ bsum) {
    __shared__ int s[256];
    int tid = threadIdx.x;
    int i = blockIdx.x * 256 + tid;
    int v = (i < N_NODES) ? cnt[i] : 0;
    s[tid] = v;
    __syncthreads();
    for (int off = 1; off < 256; off <<= 1) {
        int add = (tid >= off) ? s[tid - off] : 0;
        __syncthreads();
        s[tid] += add;
        __syncthreads();
    }
    if (i < N_NODES) rowptr[i] = s[tid] - v;
    if (tid == 255) bsum[blockIdx.x] = s[255];
}

__global__ void k_scan2(int* __restrict__ bsum) {
    __shared__ int s[256];
    int tid = threadIdx.x;
    int v = (tid < SCAN_BLOCKS) ? bsum[tid] : 0;
    s[tid] = v;
    __syncthreads();
    for (int off = 1; off < 256; off <<= 1) {
        int add = (tid >= off) ? s[tid - off] : 0;
        __syncthreads();
        s[tid] += add;
        __syncthreads();
    }
    if (tid < SCAN_BLOCKS) bsum[tid] = s[tid] - v;
}

__global__ void k_scan3(int* __restrict__ rowptr, const int* __restrict__ bsum) {
    int i = blockIdx.x * 256 + threadIdx.x;
    if (i < N_NODES) rowptr[i] += bsum[blockIdx.x];
    if (i == 0) rowptr[N_NODES] = N_EDGES;
}

// ---------------- scatter edges into CSR + accumulate normsum ----------------
__global__ void k_scatter(const int* __restrict__ src, const int* __restrict__ dst,
                          const float* __restrict__ dinv, const int* __restrict__ rowptr,
                          int* __restrict__ fill, int2* __restrict__ epair,
                          float* __restrict__ normsum) {
    int e = blockIdx.x * 256 + threadIdx.x;
    if (e >= N_EDGES) return;
    int s = src[e], d = dst[e];
    float norm = dinv[s] * dinv[d];
    int slot = rowptr[d] + atomicAdd(&fill[d], 1);
    epair[slot] = make_int2(s, __float_as_int(norm));
    atomicAdd(&normsum[d], norm);
}

// ---------------- W1 prepack (no BN): W[K][256] f32 -> [256][K] hi/lo bf16 ---
__global__ void k_pack(const float* __restrict__ W, short* __restrict__ hi,
                       short* __restrict__ lo, int K) {
    int idx = blockIdx.x * 256 + threadIdx.x;
    if (idx >= 256 * K) return;
    int n = idx / K, k = idx - n * K;
    float f = W[(size_t)k * 256 + n];
    unsigned u = __builtin_bit_cast(unsigned, f);
    hi[idx] = (short)(u >> 16);
    float hf = __builtin_bit_cast(float, u & 0xFFFF0000u);
    lo[idx] = (short)(__builtin_bit_cast(unsigned, f - hf) >> 16);
}

// ---------------- BN-folded weight pack: W' = diag(mulk)W, rowvec = addk@W ---
// one block per output column n; thread k over input rows. K=256 fixed.
__global__ __launch_bounds__(256)
void k_wfold(const float* __restrict__ W, const float* __restrict__ mulk,
             const float* __restrict__ addk, short* __restrict__ hi,
             short* __restrict__ lo, float* __restrict__ rowvec) {
    __shared__ float red[256];
    const int n = blockIdx.x;
    const int k = threadIdx.x;
    float w = W[(size_t)k * 256 + n];
    float f = w * mulk[k];
    unsigned u = __builtin_bit_cast(unsigned, f);
    hi[(size_t)n * 256 + k] = (short)(u >> 16);
    float hf = __builtin_bit_cast(float, u & 0xFFFF0000u);
    lo[(size_t)n * 256 + k] = (short)(__builtin_bit_cast(unsigned, f - hf) >> 16);
    red[k] = addk[k] * w;
    __syncthreads();
    for (int off = 128; off > 0; off >>= 1) {
        if (k < off) red[k] += red[k + off];
        __syncthreads();
    }
    if (k == 0) rowvec[n] = red[0];
}

// ---------------- split x (layer-1 input) into bf16 hi/lo -------------------
__global__ void k_splitx(const float* __restrict__ x, short* __restrict__ hi,
                         short* __restrict__ lo) {
    int idx = blockIdx.x * 256 + threadIdx.x;   // over N_NODES*128/4
    if (idx >= N_NODES * 32) return;
    float4 v = reinterpret_cast<const float4*>(x)[idx];
    float vv[4] = {v.x, v.y, v.z, v.w};
    short4v h4, l4;
    #pragma unroll
    for (int j = 0; j < 4; ++j) {
        unsigned u = __builtin_bit_cast(unsigned, vv[j]);
        h4[j] = (short)(u >> 16);
        float hf = __builtin_bit_cast(float, u & 0xFFFF0000u);
        l4[j] = (short)(__builtin_bit_cast(unsigned, vv[j] - hf) >> 16);
    }
    *reinterpret_cast<short4v*>(&hi[(size_t)idx * 4]) = h4;
    *reinterpret_cast<short4v*>(&lo[(size_t)idx * 4]) = l4;
}

// ---------------- split-bf16 MFMA GEMM, pre-split A, fp16 C ------------------
// A given as Ahi/Alo bf16 [M][K]; B as W'hi/W'lo [256][K]. No BN in kernel.
#define BK 32
__global__ __launch_bounds__(256)
void k_gemm_mfma(const short* __restrict__ Ahi, const short* __restrict__ Alo,
                 const short* __restrict__ Bhi, const short* __restrict__ Blo,
                 _Float16* __restrict__ C, int M, int K) {
    __shared__ unsigned As[2][128 * 16];
    const int tid  = threadIdx.x;
    const int lane = tid & 63;
    const int w    = tid >> 6;
    const int wr   = (w >> 1) * 64;
    const int wc   = (w & 1) * 64;
    const int bid  = blockIdx.x;
    const int bx   = (bid >> 4) * 8 + (bid & 7);   // 0..391
    const int by   = (bid >> 3) & 1;
    const int brow = bx * 128;
    const int bcol = by * 128;

    f32x4 acc[4][4];
    #pragma unroll
    for (int m = 0; m < 4; ++m)
        #pragma unroll
        for (int n = 0; n < 4; ++n) acc[m][n] = (f32x4){0.f, 0.f, 0.f, 0.f};

    const int lr = tid >> 1;
    const int lk = (tid & 1) * 16;      // bf16 index within BK
    const int grow = brow + lr;
    const bool rowok = grow < M;
    const short* Ahp = Ahi + (size_t)grow * K + lk;
    const short* Alp = Alo + (size_t)grow * K + lk;
    const int NS = K / BK;

    uint4 ph0, ph1, pl0, pl1;
    auto load_pf = [&](int s) {
        if (rowok) {
            ph0 = *reinterpret_cast<const uint4*>(Ahp + s * BK);
            ph1 = *reinterpret_cast<const uint4*>(Ahp + s * BK + 8);
            pl0 = *reinterpret_cast<const uint4*>(Alp + s * BK);
            pl1 = *reinterpret_cast<const uint4*>(Alp + s * BK + 8);
        } else {
            ph0 = ph1 = pl0 = pl1 = make_uint4(0, 0, 0, 0);
        }
    };

    load_pf(0);

    const int sw = (lr >> 1) & 3;
    const int c0 = (tid & 1) * 2;
    unsigned* dh0 = &As[0][lr * 16 + ((c0 ^ sw) << 2)];
    unsigned* dh1 = &As[0][lr * 16 + (((c0 + 1) ^ sw) << 2)];
    unsigned* dl0 = &As[1][lr * 16 + ((c0 ^ sw) << 2)];
    unsigned* dl1 = &As[1][lr * 16 + (((c0 + 1) ^ sw) << 2)];

    for (int s = 0; s < NS; ++s) {
        __syncthreads();
        *reinterpret_cast<uint4*>(dh0) = ph0;
        *reinterpret_cast<uint4*>(dh1) = ph1;
        *reinterpret_cast<uint4*>(dl0) = pl0;
        *reinterpret_cast<uint4*>(dl1) = pl1;
        if (s + 1 < NS) load_pf(s + 1);
        __syncthreads();

        short8 bh[4], bl[4];
        const int kb = s * BK + (lane >> 4) * 8;
        #pragma unroll
        for (int n = 0; n < 4; ++n) {
            int col = bcol + wc + n * 16 + (lane & 15);
            bh[n] = *reinterpret_cast<const short8*>(Bhi + (size_t)col * K + kb);
            bl[n] = *reinterpret_cast<const short8*>(Blo + (size_t)col * K + kb);
        }
        #pragma unroll
        for (int m = 0; m < 4; ++m) {
            int row = wr + m * 16 + (lane & 15);
            int c = lane >> 4;
            int sw2 = (row >> 1) & 3;
            const unsigned* ph = &As[0][row * 16 + ((c ^ sw2) << 2)];
            const unsigned* pl = &As[1][row * 16 + ((c ^ sw2) << 2)];
            short8 ah = *reinterpret_cast<const short8*>(ph);
            short8 al = *reinterpret_cast<const short8*>(pl);
            #pragma unroll
            for (int n = 0; n < 4; ++n) {
                acc[m][n] = __builtin_amdgcn_mfma_f32_16x16x32_bf16(ah, bh[n], acc[m][n], 0, 0, 0);
                acc[m][n] = __builtin_amdgcn_mfma_f32_16x16x32_bf16(al, bh[n], acc[m][n], 0, 0, 0);
                acc[m][n] = __builtin_amdgcn_mfma_f32_16x16x32_bf16(ah, bl[n], acc[m][n], 0, 0, 0);
            }
        }
    }

    #pragma unroll
    for (int m = 0; m < 4; ++m) {
        #pragma unroll
        for (int n = 0; n < 4; ++n) {
            int col = bcol + wc + n * 16 + (lane & 15);
            #pragma unroll
            for (int j = 0; j < 4; ++j) {
                int row = brow + wr + m * 16 + (lane >> 4) * 4 + j;
                if (row < M) C[(size_t)row * 256 + col] = (_Float16)acc[m][n][j];
            }
        }
    }
}

// ---------------- fused aggregation: one node per wave -----------------------
// agg = sum(norm*xw[src]) + dinv^2*xw[n]; h = relu(agg + S_n*rowvec + bias)
// MODE 0: write h split bf16 hi/lo (next GEMM's A) + BN stats (partitioned).
// MODE 1: write h fp32 to hf32 (pooled by k_pool).
#define BATCH 8
template<int MODE>
__global__ __launch_bounds__(256)
void k_agg2(const _Float16* __restrict__ xw, const float* __restrict__ dinv,
            const float* __restrict__ normsum, const int* __restrict__ rowptr,
            const int2* __restrict__ epair, const float* __restrict__ bias,
            const float* __restrict__ rowvec, short* __restrict__ hhi,
            short* __restrict__ hlo, float* __restrict__ hf32,
            float* __restrict__ stats) {
    __shared__ float red[2][4][256];
    const int lane = threadIdx.x & 63;
    const int wave = threadIdx.x >> 6;
    const int half = lane >> 5;
    const int fl   = lane & 31;          // feature block: [8*fl, 8*fl+8)
    const int n    = blockIdx.x * 4 + wave;   // grid = 12500 exact

    const h16x8* xw8 = reinterpret_cast<const h16x8*>(xw);

    float acc[8];
    if (half == 0) {
        float d = dinv[n];
        float sl = d * d;
        h16x8 sv = xw8[(size_t)n * 32 + fl];
        #pragma unroll
        for (int j = 0; j < 8; ++j) acc[j] = sl * (float)sv[j];
    } else {
        #pragma unroll
        for (int j = 0; j < 8; ++j) acc[j] = 0.f;
    }

    const int beg = rowptr[n], end = rowptr[n + 1];
    int i = beg + half;

    if (i < end) {
        int ecur[BATCH]; float wcur[BATCH];
        #pragma unroll
        for (int k = 0; k < BATCH; ++k) {
            int idx = i + 2 * k;
            bool ok = idx < end;
            int2 p = epair[ok ? idx : (end - 1)];
            ecur[k] = p.x;
            wcur[k] = ok ? __int_as_float(p.y) : 0.f;
        }
        while (true) {
            h16x8 r[BATCH];
            #pragma unroll
            for (int k = 0; k < BATCH; ++k)
                r[k] = xw8[(size_t)ecur[k] * 32 + fl];

            int inext = i + 2 * BATCH;
            bool more = inext < end;
            int enxt[BATCH]; float wnxt[BATCH];
            if (more) {
                #pragma unroll
                for (int k = 0; k < BATCH; ++k) {
                    int idx = inext + 2 * k;
                    bool ok = idx < end;
                    int2 p = epair[ok ? idx : (end - 1)];
                    enxt[k] = p.x;
                    wnxt[k] = ok ? __int_as_float(p.y) : 0.f;
                }
            }
            #pragma unroll
            for (int k = 0; k < BATCH; ++k)
                #pragma unroll
                for (int j = 0; j < 8; ++j)
                    acc[j] = fmaf(wcur[k], (float)r[k][j], acc[j]);
            if (!more) break;
            i = inext;
            #pragma unroll
            for (int k = 0; k < BATCH; ++k) { ecur[k] = enxt[k]; wcur[k] = wnxt[k]; }
        }
    }

    // merge halves
    #pragma unroll
    for (int j = 0; j < 8; ++j) acc[j] += __shfl_xor(acc[j], 32, 64);

    if (half == 0) {
        float4 b0 = *reinterpret_cast<const float4*>(&bias[fl * 8]);
        float4 b1 = *reinterpret_cast<const float4*>(&bias[fl * 8 + 4]);
        float4 r0 = *reinterpret_cast<const float4*>(&rowvec[fl * 8]);
        float4 r1 = *reinterpret_cast<const float4*>(&rowvec[fl * 8 + 4]);
        float bv[8] = {b0.x, b0.y, b0.z, b0.w, b1.x, b1.y, b1.z, b1.w};
        float rv[8] = {r0.x, r0.y, r0.z, r0.w, r1.x, r1.y, r1.z, r1.w};
        float S = normsum[n];
        #pragma unroll
        for (int j = 0; j < 8; ++j)
            acc[j] = fmaxf(acc[j] + fmaf(S, rv[j], bv[j]), 0.f);

        if (MODE == 0) {
            // split hi/lo bf16, 16B each
            unsigned hw[4], lw[4];
            #pragma unroll
            for (int p = 0; p < 4; ++p) {
                float f0 = acc[2 * p], f1 = acc[2 * p + 1];
                unsigned u0 = __builtin_bit_cast(unsigned, f0);
                unsigned u1 = __builtin_bit_cast(unsigned, f1);
                hw[p] = (u1 & 0xFFFF0000u) | (u0 >> 16);
                float h0 = __builtin_bit_cast(float, u0 & 0xFFFF0000u);
                float h1 = __builtin_bit_cast(float, u1 & 0xFFFF0000u);
                lw[p] = (__builtin_bit_cast(unsigned, f1 - h1) & 0xFFFF0000u) |
                        (__builtin_bit_cast(unsigned, f0 - h0) >> 16);
            }
            *reinterpret_cast<uint4*>(&hhi[(size_t)n * 256 + fl * 8]) =
                make_uint4(hw[0], hw[1], hw[2], hw[3]);
            *reinterpret_cast<uint4*>(&hlo[(size_t)n * 256 + fl * 8]) =
                make_uint4(lw[0], lw[1], lw[2], lw[3]);
            float4 o0 = make_float4(acc[0], acc[1], acc[2], acc[3]);
            float4 o1 = make_float4(acc[4], acc[5], acc[6], acc[7]);
            float4 q0 = make_float4(acc[0]*acc[0], acc[1]*acc[1], acc[2]*acc[2], acc[3]*acc[3]);
            float4 q1 = make_float4(acc[4]*acc[4], acc[5]*acc[5], acc[6]*acc[6], acc[7]*acc[7]);
            *reinterpret_cast<float4*>(&red[0][wave][fl * 8])     = o0;
            *reinterpret_cast<float4*>(&red[0][wave][fl * 8 + 4]) = o1;
            *reinterpret_cast<float4*>(&red[1][wave][fl * 8])     = q0;
            *reinterpret_cast<float4*>(&red[1][wave][fl * 8 + 4]) = q1;
        } else {
            *reinterpret_cast<float4*>(&hf32[(size_t)n * 256 + fl * 8]) =
                make_float4(acc[0], acc[1], acc[2], acc[3]);
            *reinterpret_cast<float4*>(&hf32[(size_t)n * 256 + fl * 8 + 4]) =
                make_float4(acc[4], acc[5], acc[6], acc[7]);
        }
    }

    if (MODE == 0) {
        __syncthreads();
        int t = threadIdx.x;
        float s = red[0][0][t] + red[0][1][t] + red[0][2][t] + red[0][3][t];
        float q = red[1][0][t] + red[1][1][t] + red[1][2][t] + red[1][3][t];
        float* part = stats + (size_t)(blockIdx.x & (NPART - 1)) * 512;
        atomicAdd(&part[t], s);
        atomicAdd(&part[256 + t], q);
    }
}

// finalize: sum partitions -> mulk/addk
__global__ void k_bnfinalize(const float* __restrict__ stats,
                             const float* __restrict__ gamma, const float* __restrict__ beta,
                             float* __restrict__ mulk, float* __restrict__ addk) {
    int f = threadIdx.x;
    float s = 0.f, q = 0.f;
    for (int p = 0; p < NPART; ++p) {
        s += stats[(size_t)p * 512 + f];
        q += stats[(size_t)p * 512 + 256 + f];
    }
    float m = s * (1.0f / N_NODES);
    float var = q * (1.0f / N_NODES) - m * m;
    float sc = gamma[f] * rsqrtf(var + BN_EPS);
    mulk[f] = sc;
    addk[f] = beta[f] - m * sc;
}

// ---------------- global_add_pool (run-length + atomics) ---------------------
template<int ROWS>
__global__ __launch_bounds__(256)
void k_pool(const float* __restrict__ h, const int* __restrict__ batch,
            float* __restrict__ out) {
    const int f = threadIdx.x;
    const int r0 = blockIdx.x * ROWS;
    float acc = 0.f;
    int cur = -1;
    for (int i = 0; i < ROWS; ++i) {
        int n = r0 + i;
        if (n >= N_NODES) break;
        int g = batch[n];
        float v = h[(size_t)n * F + f];
        if (g != cur) {
            if (cur >= 0) atomicAdd(&out[(size_t)cur * F + f], acc);
            cur = g; acc = v;
        } else {
            acc += v;
        }
    }
    if (cur >= 0) atomicAdd(&out[(size_t)cur * F + f], acc);
}

// ---------------- host ----------------
extern "C" void kernel_launch(void* const* d_in, const int* in_sizes, int n_in,
                              void* d_out, int out_size, void* d_ws, size_t ws_size,
                              hipStream_t stream) {
    const float* x     = (const float*)d_in[0];
    const int*   ei    = (const int*)d_in[1];
    const int*   batch = (const int*)d_in[2];
    const float* W[6], *bias[6], *gamma[5], *beta[5];
    for (int i = 0; i < 6; ++i) {
        W[i]    = (const float*)d_in[3 + 2 * i];
        bias[i] = (const float*)d_in[4 + 2 * i];
    }
    for (int i = 0; i < 5; ++i) {
        gamma[i] = (const float*)d_in[15 + 2 * i];
        beta[i]  = (const float*)d_in[16 + 2 * i];
    }
    float* out = (float*)d_out;

    char* ws = (char*)d_ws;
    size_t off = 0;
    auto alloc = [&](size_t bytes) {
        void* p = ws + off;
        off = (off + bytes + 255) & ~(size_t)255;
        return p;
    };
    int*   cnt      = (int*)  alloc(N_NODES * 4);
    int*   rowptr   = (int*)  alloc((N_NODES + 1) * 4);
    int*   bsum     = (int*)  alloc(256 * 4);
    float* dinv     = (float*)alloc(N_NODES * 4);
    float* normsum  = (float*)alloc(N_NODES * 4);
    int2*  epair    = (int2*) alloc((size_t)N_EDGES * 8);
    float* mulk     = (float*)alloc(F * 4);
    float* addk     = (float*)alloc(F * 4);
    float* rowvec   = (float*)alloc(F * 4);
    float* statsAll = (float*)alloc((size_t)5 * NPART * 512 * 4);   // 640 KB
    short* Whi[6]; short* Wlo[6];
    for (int l = 0; l < 6; ++l) {
        int K = (l == 0) ? 128 : 256;
        Whi[l] = (short*)alloc((size_t)256 * K * 2);
        Wlo[l] = (short*)alloc((size_t)256 * K * 2);
    }
    short* xhi = (short*)alloc((size_t)N_NODES * 128 * 2);   // 12.8 MB
    short* xlo = (short*)alloc((size_t)N_NODES * 128 * 2);
    short* hhi = (short*)alloc((size_t)N_NODES * F * 2);     // 25.6 MB
    short* hlo = (short*)alloc((size_t)N_NODES * F * 2);
    _Float16* xw   = (_Float16*)alloc((size_t)N_NODES * F * 2);   // 25.6 MB
    float*    hfin = (float*)   alloc((size_t)N_NODES * F * 4);   // 51.2 MB

    const int* src = ei;
    const int* dst = ei + N_EDGES;

    // ---- CSR build + dinv/normsum + packs ----
    hipMemsetAsync(cnt, 0, N_NODES * 4, stream);
    hipMemsetAsync(out, 0, (size_t)N_GRAPHS * F * 4, stream);
    hipMemsetAsync(rowvec, 0, F * 4, stream);                     // layer-1 rowvec = 0
    hipMemsetAsync(statsAll, 0, (size_t)5 * NPART * 512 * 4, stream);
    k_hist<<<(N_EDGES + 255) / 256, 256, 0, stream>>>(dst, cnt);
    k_dinv<<<(N_NODES + 255) / 256, 256, 0, stream>>>(cnt, dinv, normsum);
    k_scan1<<<SCAN_BLOCKS, 256, 0, stream>>>(cnt, rowptr, bsum);
    k_scan2<<<1, 256, 0, stream>>>(bsum);
    k_scan3<<<SCAN_BLOCKS, 256, 0, stream>>>(rowptr, bsum);
    hipMemsetAsync(cnt, 0, N_NODES * 4, stream);
    k_scatter<<<(N_EDGES + 255) / 256, 256, 0, stream>>>(src, dst, dinv, rowptr, cnt,
                                                         epair, normsum);
    k_pack<<<(256 * 128 + 255) / 256, 256, 0, stream>>>(W[0], Whi[0], Wlo[0], 128);
    k_splitx<<<(N_NODES * 32 + 255) / 256, 256, 0, stream>>>(x, xhi, xlo);

    const int aggGrid = N_NODES / 4;     // 12500 blocks of 4 waves
    for (int l = 0; l < 6; ++l) {
        const int K = (l == 0) ? 128 : 256;
        const short* Ah = (l == 0) ? xhi : hhi;
        const short* Al = (l == 0) ? xlo : hlo;
        k_gemm_mfma<<<784, 256, 0, stream>>>(Ah, Al, Whi[l], Wlo[l], xw, N_NODES, K);

        if (l < 5) {
            float* stats = statsAll + (size_t)l * NPART * 512;
            k_agg2<0><<<aggGrid, 256, 0, stream>>>(xw, dinv, normsum, rowptr, epair,
                                                   bias[l], rowvec, hhi, hlo, nullptr, stats);
            k_bnfinalize<<<1, F, 0, stream>>>(stats, gamma[l], beta[l], mulk, addk);
            // fold BN into next layer's weights + rowvec
            k_wfold<<<256, 256, 0, stream>>>(W[l + 1], mulk, addk,
                                             Whi[l + 1], Wlo[l + 1], rowvec);
        } else {
            k_agg2<1><<<aggGrid, 256, 0, stream>>>(xw, dinv, normsum, rowptr, epair,
                                                   bias[l], rowvec, nullptr, nullptr,
                                                   hfin, nullptr);
            k_pool<128><<<(N_NODES + 127) / 128, 256, 0, stream>>>(hfin, batch, out);
        }
    }
}

// Round 8
// 1076.324 us; speedup vs baseline: 1.2907x; 1.0640x over previous
//
#include <hip/hip_runtime.h>

#define N_NODES 50000
#define N_EDGES 800000
#define N_GRAPHS 500
#define BN_EPS 1e-5f
#define F 256
#define SCAN_BLOCKS ((N_NODES + 255) / 256)   // 196
#define NPART 64                              // stats atomic partitions

typedef short short8 __attribute__((ext_vector_type(8)));
typedef short short4v __attribute__((ext_vector_type(4)));
typedef float f32x4 __attribute__((ext_vector_type(4)));
typedef _Float16 h16x8 __attribute__((ext_vector_type(8)));

// ---------------- degree histogram (4 edges/thread) ----------------
__global__ void k_hist(const int* __restrict__ dst, int* __restrict__ cnt) {
    int e0 = (blockIdx.x * blockDim.x + threadIdx.x) * 4;
    if (e0 >= N_EDGES) return;
    int4 d4 = *reinterpret_cast<const int4*>(&dst[e0]);
    atomicAdd(&cnt[d4.x], 1);
    atomicAdd(&cnt[d4.y], 1);
    atomicAdd(&cnt[d4.z], 1);
    atomicAdd(&cnt[d4.w], 1);
}

__global__ void k_dinv(const int* __restrict__ cnt, float* __restrict__ dinv) {
    int n = blockIdx.x * blockDim.x + threadIdx.x;
    if (n < N_NODES) dinv[n] = rsqrtf((float)cnt[n] + 1.0f);
}

// ---------------- prefix scan ----------------
__global__ void k_scan1(const int* __restrict__ cnt, int* __restrict__ rowptr,
                        int* __restrict__ bsum) {
    __shared__ int s[256];
    int tid = threadIdx.x;
    int i = blockIdx.x * 256 + tid;
    int v = (i < N_NODES) ? cnt[i] : 0;
    s[tid] = v;
    __syncthreads();
    for (int off = 1; off < 256; off <<= 1) {
        int add = (tid >= off) ? s[tid - off] : 0;
        __syncthreads();
        s[tid] += add;
        __syncthreads();
    }
    if (i < N_NODES) rowptr[i] = s[tid] - v;
    if (tid == 255) bsum[blockIdx.x] = s[255];
}

__global__ void k_scan2(int* __restrict__ bsum) {
    __shared__ int s[256];
    int tid = threadIdx.x;
    int v = (tid < SCAN_BLOCKS) ? bsum[tid] : 0;
    s[tid] = v;
    __syncthreads();
    for (int off = 1; off < 256; off <<= 1) {
        int add = (tid >= off) ? s[tid - off] : 0;
        __syncthreads();
        s[tid] += add;
        __syncthreads();
    }
    if (tid < SCAN_BLOCKS) bsum[tid] = s[tid] - v;
}

__global__ void k_scan3(int* __restrict__ rowptr, const int* __restrict__ bsum) {
    int i = blockIdx.x * 256 + threadIdx.x;
    if (i < N_NODES) rowptr[i] += bsum[blockIdx.x];
    if (i == 0) rowptr[N_NODES] = N_EDGES;
}

// ---------------- scatter edges into CSR (4 edges/thread) --------------------
// fillptr is a live copy of rowptr (slots allocated via atomicAdd).
__global__ void k_scatter(const int* __restrict__ src, const int* __restrict__ dst,
                          const float* __restrict__ dinv, int* __restrict__ fillptr,
                          int2* __restrict__ epair) {
    int e0 = (blockIdx.x * blockDim.x + threadIdx.x) * 4;
    if (e0 >= N_EDGES) return;
    int4 s4 = *reinterpret_cast<const int4*>(&src[e0]);
    int4 d4 = *reinterpret_cast<const int4*>(&dst[e0]);
    int ss[4] = {s4.x, s4.y, s4.z, s4.w};
    int dd[4] = {d4.x, d4.y, d4.z, d4.w};
    #pragma unroll
    for (int j = 0; j < 4; ++j) {
        float norm = dinv[ss[j]] * dinv[dd[j]];
        int slot = atomicAdd(&fillptr[dd[j]], 1);
        epair[slot] = make_int2(ss[j], __float_as_int(norm));
    }
}

// ---------------- W1 prepack (no BN): W[K][256] f32 -> [256][K] hi/lo bf16 ---
__global__ void k_pack(const float* __restrict__ W, short* __restrict__ hi,
                       short* __restrict__ lo, int K) {
    int idx = blockIdx.x * 256 + threadIdx.x;
    if (idx >= 256 * K) return;
    int n = idx / K, k = idx - n * K;
    float f = W[(size_t)k * 256 + n];
    unsigned u = __builtin_bit_cast(unsigned, f);
    hi[idx] = (short)(u >> 16);
    float hf = __builtin_bit_cast(float, u & 0xFFFF0000u);
    lo[idx] = (short)(__builtin_bit_cast(unsigned, f - hf) >> 16);
}

// ---------------- BN-finalize + weight fold in one kernel --------------------
// block n (output col), thread k (input row). Reads raw partitioned stats.
__global__ __launch_bounds__(256)
void k_wfold(const float* __restrict__ W, const float* __restrict__ stats,
             const float* __restrict__ gamma, const float* __restrict__ beta,
             short* __restrict__ hi, short* __restrict__ lo,
             float* __restrict__ rowvec) {
    __shared__ float red[256];
    const int n = blockIdx.x;
    const int k = threadIdx.x;
    float s = 0.f, q = 0.f;
    for (int p = 0; p < NPART; ++p) {
        s += stats[(size_t)p * 512 + k];
        q += stats[(size_t)p * 512 + 256 + k];
    }
    float m = s * (1.0f / N_NODES);
    float var = q * (1.0f / N_NODES) - m * m;
    float mulk = gamma[k] * rsqrtf(var + BN_EPS);
    float addk = beta[k] - m * mulk;
    float w = W[(size_t)k * 256 + n];
    float f = w * mulk;
    unsigned u = __builtin_bit_cast(unsigned, f);
    hi[(size_t)n * 256 + k] = (short)(u >> 16);
    float hf = __builtin_bit_cast(float, u & 0xFFFF0000u);
    lo[(size_t)n * 256 + k] = (short)(__builtin_bit_cast(unsigned, f - hf) >> 16);
    red[k] = addk * w;
    __syncthreads();
    for (int off = 128; off > 0; off >>= 1) {
        if (k < off) red[k] += red[k + off];
        __syncthreads();
    }
    if (k == 0) rowvec[n] = red[0];
}

// ---------------- split x (layer-1 input) into bf16 hi/lo -------------------
__global__ void k_splitx(const float* __restrict__ x, short* __restrict__ hi,
                         short* __restrict__ lo) {
    int idx = blockIdx.x * 256 + threadIdx.x;   // over N_NODES*128/4
    if (idx >= N_NODES * 32) return;
    float4 v = reinterpret_cast<const float4*>(x)[idx];
    float vv[4] = {v.x, v.y, v.z, v.w};
    short4v h4, l4;
    #pragma unroll
    for (int j = 0; j < 4; ++j) {
        unsigned u = __builtin_bit_cast(unsigned, vv[j]);
        h4[j] = (short)(u >> 16);
        float hf = __builtin_bit_cast(float, u & 0xFFFF0000u);
        l4[j] = (short)(__builtin_bit_cast(unsigned, vv[j] - hf) >> 16);
    }
    *reinterpret_cast<short4v*>(&hi[(size_t)idx * 4]) = h4;
    *reinterpret_cast<short4v*>(&lo[(size_t)idx * 4]) = l4;
}

// ---------------- split-bf16 MFMA GEMM, double-buffered, 1 barrier/K-step ----
#define BK 32
__global__ __launch_bounds__(256)
void k_gemm_mfma(const short* __restrict__ Ahi, const short* __restrict__ Alo,
                 const short* __restrict__ Bhi, const short* __restrict__ Blo,
                 _Float16* __restrict__ C, int M, int K) {
    __shared__ unsigned As[2][2][128 * 16];   // [buf][hi/lo][row*16 + unit*4]
    const int tid  = threadIdx.x;
    const int lane = tid & 63;
    const int w    = tid >> 6;
    const int wr   = (w >> 1) * 64;
    const int wc   = (w & 1) * 64;
    const int bid  = blockIdx.x;
    const int bx   = (bid >> 4) * 8 + (bid & 7);   // 0..391
    const int by   = (bid >> 3) & 1;
    const int brow = bx * 128;
    const int bcol = by * 128;

    f32x4 acc[4][4];
    #pragma unroll
    for (int m = 0; m < 4; ++m)
        #pragma unroll
        for (int n = 0; n < 4; ++n) acc[m][n] = (f32x4){0.f, 0.f, 0.f, 0.f};

    const int lr = tid >> 1;
    const int lk = (tid & 1) * 16;      // bf16 index within BK
    const int grow = brow + lr;
    const bool rowok = grow < M;
    const short* Ahp = Ahi + (size_t)grow * K + lk;
    const short* Alp = Alo + (size_t)grow * K + lk;
    const int NS = K / BK;

    uint4 ph0, ph1, pl0, pl1;
    auto load_pf = [&](int s) {
        if (rowok) {
            ph0 = *reinterpret_cast<const uint4*>(Ahp + s * BK);
            ph1 = *reinterpret_cast<const uint4*>(Ahp + s * BK + 8);
            pl0 = *reinterpret_cast<const uint4*>(Alp + s * BK);
            pl1 = *reinterpret_cast<const uint4*>(Alp + s * BK + 8);
        } else {
            ph0 = ph1 = pl0 = pl1 = make_uint4(0, 0, 0, 0);
        }
    };

    const int sw  = (lr >> 1) & 3;
    const int c0  = (tid & 1) * 2;
    const int off0 = lr * 16 + ((c0 ^ sw) << 2);
    const int off1 = lr * 16 + (((c0 + 1) ^ sw) << 2);

    // prologue: stage s=0 into buf 0
    load_pf(0);
    *reinterpret_cast<uint4*>(&As[0][0][off0]) = ph0;
    *reinterpret_cast<uint4*>(&As[0][0][off1]) = ph1;
    *reinterpret_cast<uint4*>(&As[0][1][off0]) = pl0;
    *reinterpret_cast<uint4*>(&As[0][1][off1]) = pl1;

    for (int s = 0; s < NS; ++s) {
        const int cur = s & 1;
        if (s + 1 < NS) load_pf(s + 1);         // issue next global loads
        __syncthreads();                         // buf[cur] writes visible

        short8 bh[4], bl[4];
        const int kb = s * BK + (lane >> 4) * 8;
        #pragma unroll
        for (int n = 0; n < 4; ++n) {
            int col = bcol + wc + n * 16 + (lane & 15);
            bh[n] = *reinterpret_cast<const short8*>(Bhi + (size_t)col * K + kb);
            bl[n] = *reinterpret_cast<const short8*>(Blo + (size_t)col * K + kb);
        }
        #pragma unroll
        for (int m = 0; m < 4; ++m) {
            int row = wr + m * 16 + (lane & 15);
            int c = lane >> 4;
            int sw2 = (row >> 1) & 3;
            const unsigned* ph = &As[cur][0][row * 16 + ((c ^ sw2) << 2)];
            const unsigned* pl = &As[cur][1][row * 16 + ((c ^ sw2) << 2)];
            short8 ah = *reinterpret_cast<const short8*>(ph);
            short8 al = *reinterpret_cast<const short8*>(pl);
            #pragma unroll
            for (int n = 0; n < 4; ++n) {
                acc[m][n] = __builtin_amdgcn_mfma_f32_16x16x32_bf16(ah, bh[n], acc[m][n], 0, 0, 0);
                acc[m][n] = __builtin_amdgcn_mfma_f32_16x16x32_bf16(al, bh[n], acc[m][n], 0, 0, 0);
                acc[m][n] = __builtin_amdgcn_mfma_f32_16x16x32_bf16(ah, bl[n], acc[m][n], 0, 0, 0);
            }
        }
        if (s + 1 < NS) {                        // stage next into alt buffer
            *reinterpret_cast<uint4*>(&As[cur ^ 1][0][off0]) = ph0;
            *reinterpret_cast<uint4*>(&As[cur ^ 1][0][off1]) = ph1;
            *reinterpret_cast<uint4*>(&As[cur ^ 1][1][off0]) = pl0;
            *reinterpret_cast<uint4*>(&As[cur ^ 1][1][off1]) = pl1;
        }
    }

    #pragma unroll
    for (int m = 0; m < 4; ++m) {
        #pragma unroll
        for (int n = 0; n < 4; ++n) {
            int col = bcol + wc + n * 16 + (lane & 15);
            #pragma unroll
            for (int j = 0; j < 4; ++j) {
                int row = brow + wr + m * 16 + (lane >> 4) * 4 + j;
                if (row < M) C[(size_t)row * 256 + col] = (_Float16)acc[m][n][j];
            }
        }
    }
}

// ---------------- fused aggregation: one node per wave -----------------------
// agg = sum(norm*xw[src]) + dinv^2*xw[n]; S = dinv^2 + sum(norm) (in-register)
// h = relu(agg + S*rowvec + bias)
// MODE 0: write h split bf16 hi/lo + BN stats (partitioned atomics).
// MODE 1: write h fp32 (pooled by k_pool).
#define BATCH 8
template<int MODE>
__global__ __launch_bounds__(256)
void k_agg2(const _Float16* __restrict__ xw, const float* __restrict__ dinv,
            const int* __restrict__ rowptr, const int2* __restrict__ epair,
            const float* __restrict__ bias, const float* __restrict__ rowvec,
            short* __restrict__ hhi, short* __restrict__ hlo,
            float* __restrict__ hf32, float* __restrict__ stats) {
    __shared__ float red[2][4][256];
    const int lane = threadIdx.x & 63;
    const int wave = threadIdx.x >> 6;
    const int half = lane >> 5;
    const int fl   = lane & 31;          // feature block: [8*fl, 8*fl+8)
    const int n    = blockIdx.x * 4 + wave;   // grid = 12500 exact

    const h16x8* xw8 = reinterpret_cast<const h16x8*>(xw);

    float acc[8];
    float wsum;
    if (half == 0) {
        float d = dinv[n];
        float sl = d * d;
        h16x8 sv = xw8[(size_t)n * 32 + fl];
        #pragma unroll
        for (int j = 0; j < 8; ++j) acc[j] = sl * (float)sv[j];
        wsum = sl;
    } else {
        #pragma unroll
        for (int j = 0; j < 8; ++j) acc[j] = 0.f;
        wsum = 0.f;
    }

    const int beg = rowptr[n], end = rowptr[n + 1];
    int i = beg + half;

    if (i < end) {
        int ecur[BATCH]; float wcur[BATCH];
        #pragma unroll
        for (int k = 0; k < BATCH; ++k) {
            int idx = i + 2 * k;
            bool ok = idx < end;
            int2 p = epair[ok ? idx : (end - 1)];
            ecur[k] = p.x;
            wcur[k] = ok ? __int_as_float(p.y) : 0.f;
        }
        while (true) {
            h16x8 r[BATCH];
            #pragma unroll
            for (int k = 0; k < BATCH; ++k)
                r[k] = xw8[(size_t)ecur[k] * 32 + fl];

            int inext = i + 2 * BATCH;
            bool more = inext < end;
            int enxt[BATCH]; float wnxt[BATCH];
            if (more) {
                #pragma unroll
                for (int k = 0; k < BATCH; ++k) {
                    int idx = inext + 2 * k;
                    bool ok = idx < end;
                    int2 p = epair[ok ? idx : (end - 1)];
                    enxt[k] = p.x;
                    wnxt[k] = ok ? __int_as_float(p.y) : 0.f;
                }
            }
            #pragma unroll
            for (int k = 0; k < BATCH; ++k) {
                wsum += wcur[k];
                #pragma unroll
                for (int j = 0; j < 8; ++j)
                    acc[j] = fmaf(wcur[k], (float)r[k][j], acc[j]);
            }
            if (!more) break;
            i = inext;
            #pragma unroll
            for (int k = 0; k < BATCH; ++k) { ecur[k] = enxt[k]; wcur[k] = wnxt[k]; }
        }
    }

    // merge halves
    #pragma unroll
    for (int j = 0; j < 8; ++j) acc[j] += __shfl_xor(acc[j], 32, 64);
    wsum += __shfl_xor(wsum, 32, 64);

    if (half == 0) {
        float4 b0 = *reinterpret_cast<const float4*>(&bias[fl * 8]);
        float4 b1 = *reinterpret_cast<const float4*>(&bias[fl * 8 + 4]);
        float4 r0 = *reinterpret_cast<const float4*>(&rowvec[fl * 8]);
        float4 r1 = *reinterpret_cast<const float4*>(&rowvec[fl * 8 + 4]);
        float bv[8] = {b0.x, b0.y, b0.z, b0.w, b1.x, b1.y, b1.z, b1.w};
        float rv[8] = {r0.x, r0.y, r0.z, r0.w, r1.x, r1.y, r1.z, r1.w};
        #pragma unroll
        for (int j = 0; j < 8; ++j)
            acc[j] = fmaxf(acc[j] + fmaf(wsum, rv[j], bv[j]), 0.f);

        if (MODE == 0) {
            unsigned hw[4], lw[4];
            #pragma unroll
            for (int p = 0; p < 4; ++p) {
                float f0 = acc[2 * p], f1 = acc[2 * p + 1];
                unsigned u0 = __builtin_bit_cast(unsigned, f0);
                unsigned u1 = __builtin_bit_cast(unsigned, f1);
                hw[p] = (u1 & 0xFFFF0000u) | (u0 >> 16);
                float h0 = __builtin_bit_cast(float, u0 & 0xFFFF0000u);
                float h1 = __builtin_bit_cast(float, u1 & 0xFFFF0000u);
                lw[p] = (__builtin_bit_cast(unsigned, f1 - h1) & 0xFFFF0000u) |
                        (__builtin_bit_cast(unsigned, f0 - h0) >> 16);
            }
            *reinterpret_cast<uint4*>(&hhi[(size_t)n * 256 + fl * 8]) =
                make_uint4(hw[0], hw[1], hw[2], hw[3]);
            *reinterpret_cast<uint4*>(&hlo[(size_t)n * 256 + fl * 8]) =
                make_uint4(lw[0], lw[1], lw[2], lw[3]);
            float4 o0 = make_float4(acc[0], acc[1], acc[2], acc[3]);
            float4 o1 = make_float4(acc[4], acc[5], acc[6], acc[7]);
            float4 q0 = make_float4(acc[0]*acc[0], acc[1]*acc[1], acc[2]*acc[2], acc[3]*acc[3]);
            float4 q1 = make_float4(acc[4]*acc[4], acc[5]*acc[5], acc[6]*acc[6], acc[7]*acc[7]);
            *reinterpret_cast<float4*>(&red[0][wave][fl * 8])     = o0;
            *reinterpret_cast<float4*>(&red[0][wave][fl * 8 + 4]) = o1;
            *reinterpret_cast<float4*>(&red[1][wave][fl * 8])     = q0;
            *reinterpret_cast<float4*>(&red[1][wave][fl * 8 + 4]) = q1;
        } else {
            *reinterpret_cast<float4*>(&hf32[(size_t)n * 256 + fl * 8]) =
                make_float4(acc[0], acc[1], acc[2], acc[3]);
            *reinterpret_cast<float4*>(&hf32[(size_t)n * 256 + fl * 8 + 4]) =
                make_float4(acc[4], acc[5], acc[6], acc[7]);
        }
    }

    if (MODE == 0) {
        __syncthreads();
        int t = threadIdx.x;
        float s = red[0][0][t] + red[0][1][t] + red[0][2][t] + red[0][3][t];
        float q = red[1][0][t] + red[1][1][t] + red[1][2][t] + red[1][3][t];
        float* part = stats + (size_t)(blockIdx.x & (NPART - 1)) * 512;
        atomicAdd(&part[t], s);
        atomicAdd(&part[256 + t], q);
    }
}

// ---------------- global_add_pool (run-length + atomics) ---------------------
template<int ROWS>
__global__ __launch_bounds__(256)
void k_pool(const float* __restrict__ h, const int* __restrict__ batch,
            float* __restrict__ out) {
    const int f = threadIdx.x;
    const int r0 = blockIdx.x * ROWS;
    float acc = 0.f;
    int cur = -1;
    for (int i = 0; i < ROWS; ++i) {
        int n = r0 + i;
        if (n >= N_NODES) break;
        int g = batch[n];
        float v = h[(size_t)n * F + f];
        if (g != cur) {
            if (cur >= 0) atomicAdd(&out[(size_t)cur * F + f], acc);
            cur = g; acc = v;
        } else {
            acc += v;
        }
    }
    if (cur >= 0) atomicAdd(&out[(size_t)cur * F + f], acc);
}

// ---------------- host ----------------
extern "C" void kernel_launch(void* const* d_in, const int* in_sizes, int n_in,
                              void* d_out, int out_size, void* d_ws, size_t ws_size,
                              hipStream_t stream) {
    const float* x     = (const float*)d_in[0];
    const int*   ei    = (const int*)d_in[1];
    const int*   batch = (const int*)d_in[2];
    const float* W[6], *bias[6], *gamma[5], *beta[5];
    for (int i = 0; i < 6; ++i) {
        W[i]    = (const float*)d_in[3 + 2 * i];
        bias[i] = (const float*)d_in[4 + 2 * i];
    }
    for (int i = 0; i < 5; ++i) {
        gamma[i] = (const float*)d_in[15 + 2 * i];
        beta[i]  = (const float*)d_in[16 + 2 * i];
    }
    float* out = (float*)d_out;

    char* ws = (char*)d_ws;
    size_t off = 0;
    auto alloc = [&](size_t bytes) {
        void* p = ws + off;
        off = (off + bytes + 255) & ~(size_t)255;
        return p;
    };
    int*   cnt      = (int*)  alloc(N_NODES * 4);
    int*   rowptr   = (int*)  alloc((N_NODES + 1) * 4);
    int*   fillptr  = (int*)  alloc(N_NODES * 4);
    int*   bsum     = (int*)  alloc(256 * 4);
    float* dinv     = (float*)alloc(N_NODES * 4);
    int2*  epair    = (int2*) alloc((size_t)N_EDGES * 8);
    float* rowvec   = (float*)alloc(F * 4);
    float* statsAll = (float*)alloc((size_t)5 * NPART * 512 * 4);   // 640 KB
    short* Whi[6]; short* Wlo[6];
    for (int l = 0; l < 6; ++l) {
        int K = (l == 0) ? 128 : 256;
        Whi[l] = (short*)alloc((size_t)256 * K * 2);
        Wlo[l] = (short*)alloc((size_t)256 * K * 2);
    }
    short* xhi = (short*)alloc((size_t)N_NODES * 128 * 2);   // 12.8 MB
    short* xlo = (short*)alloc((size_t)N_NODES * 128 * 2);
    short* hhi = (short*)alloc((size_t)N_NODES * F * 2);     // 25.6 MB
    short* hlo = (short*)alloc((size_t)N_NODES * F * 2);
    _Float16* xw   = (_Float16*)alloc((size_t)N_NODES * F * 2);   // 25.6 MB
    float*    hfin = (float*)   alloc((size_t)N_NODES * F * 4);   // 51.2 MB

    const int* src = ei;
    const int* dst = ei + N_EDGES;

    // ---- CSR build + dinv + packs ----
    hipMemsetAsync(cnt, 0, N_NODES * 4, stream);
    hipMemsetAsync(out, 0, (size_t)N_GRAPHS * F * 4, stream);
    hipMemsetAsync(rowvec, 0, F * 4, stream);                     // layer-1 rowvec = 0
    hipMemsetAsync(statsAll, 0, (size_t)5 * NPART * 512 * 4, stream);
    k_hist<<<(N_EDGES / 4 + 255) / 256, 256, 0, stream>>>(dst, cnt);
    k_dinv<<<(N_NODES + 255) / 256, 256, 0, stream>>>(cnt, dinv);
    k_scan1<<<SCAN_BLOCKS, 256, 0, stream>>>(cnt, rowptr, bsum);
    k_scan2<<<1, 256, 0, stream>>>(bsum);
    k_scan3<<<SCAN_BLOCKS, 256, 0, stream>>>(rowptr, bsum);
    hipMemcpyAsync(fillptr, rowptr, N_NODES * 4, hipMemcpyDeviceToDevice, stream);
    k_scatter<<<(N_EDGES / 4 + 255) / 256, 256, 0, stream>>>(src, dst, dinv, fillptr, epair);
    k_pack<<<(256 * 128 + 255) / 256, 256, 0, stream>>>(W[0], Whi[0], Wlo[0], 128);
    k_splitx<<<(N_NODES * 32 + 255) / 256, 256, 0, stream>>>(x, xhi, xlo);

    const int aggGrid = N_NODES / 4;     // 12500 blocks of 4 waves
    for (int l = 0; l < 6; ++l) {
        const int K = (l == 0) ? 128 : 256;
        const short* Ah = (l == 0) ? xhi : hhi;
        const short* Al = (l == 0) ? xlo : hlo;
        k_gemm_mfma<<<784, 256, 0, stream>>>(Ah, Al, Whi[l], Wlo[l], xw, N_NODES, K);

        if (l < 5) {
            float* stats = statsAll + (size_t)l * NPART * 512;
            k_agg2<0><<<aggGrid, 256, 0, stream>>>(xw, dinv, rowptr, epair,
                                                   bias[l], rowvec, hhi, hlo,
                                                   nullptr, stats);
            // BN-finalize + fold into next layer's weights + rowvec (one kernel)
            k_wfold<<<256, 256, 0, stream>>>(W[l + 1], stats, gamma[l], beta[l],
                                             Whi[l + 1], Wlo[l + 1], rowvec);
        } else {
            k_agg2<1><<<aggGrid, 256, 0, stream>>>(xw, dinv, rowptr, epair,
                                                   bias[l], rowvec, nullptr, nullptr,
                                                   hfin, nullptr);
            k_pool<128><<<(N_NODES + 127) / 128, 256, 0, stream>>>(hfin, batch, out);
        }
    }
}